// Round 2
// baseline (4113.609 us; speedup 1.0000x reference)
//
#include <hip/hip_runtime.h>
#include <cstdint>
#include <cstddef>

// QLSTM on MI355X. Persistent kernel, 64 WGs (4 batch-groups x 16 hidden-
// slices), 1 block/CU by capacity. Weights resident in VGPRs/AGPRs (bf16
// B-fragments).
//
// R2: cross-block h exchange with SELF-VALIDATING DATA — every published h
// dword (2 bf16) is packed into a u64 with the step tag in the high dword and
// written with a single relaxed agent-scope atomic store. Consumers poll the
// data words directly until tag == t. This fuses {flag publish, flag detect,
// h load} into ONE coherent-point round trip and removes every __syncthreads
// and every vmcnt-drain from the step loop. Waves proceed fully decoupled;
// wave-convergence before MFMA is implicit in the divergent poll loop.
//
// 2-slot ping-pong overwrite safety (barrier-free): a producer writes tag t+2
// only after consuming all of h(t+1); any consumer publishes its h(t+1) slice
// only after it finished reading h(t); hence nobody can overwrite h(t) while
// it is still being read.
//
// Replay safety: prep rewrites slot0 = h0 (tag 0) and slot1 = poison tag
// 0xFFFFFFFF (matches no t in [0,512]), so stale tags from a previous graph
// replay can never satisfy a poll.

#define SEQ 512
#define BATCH 256
#define IN_DIMX 256
#define HIDN 256
#define DTOT 512

typedef float f32x4 __attribute__((ext_vector_type(4)));
typedef short s16x8 __attribute__((ext_vector_type(8)));

__device__ __forceinline__ unsigned short f2bf(float f) {
  unsigned u = __builtin_bit_cast(unsigned, f);
  u += 0x7FFFu + ((u >> 16) & 1u);   // RNE to bf16
  return (unsigned short)(u >> 16);
}

__device__ __forceinline__ float sigm(float x) {
  return __builtin_amdgcn_rcpf(1.0f + __expf(-x));
}
__device__ __forceinline__ float tanh_fast(float x) {
  return 1.0f - 2.0f * __builtin_amdgcn_rcpf(1.0f + __expf(2.0f * x));
}

// thbuf: u64 [2 slot][4 bm][32 kc][64 row][4 q]
//   lo32 = bf16 pair (h[row, kc*8+2q], h[row, kc*8+2q+1]), hi32 = step tag.
// Slot s holds h(t) for t with (t & 1) == s.
__global__ void qlstm_prep(const float* __restrict__ h0,
                           unsigned long long* __restrict__ thbuf) {
  int tid = blockIdx.x * blockDim.x + threadIdx.x;   // 65536 threads
  if (tid >= 32768) return;
  int bm = tid >> 13, rem = tid & 8191;
  int kc = rem >> 8, row = (rem >> 2) & 63, q = rem & 3;
  float a = h0[(size_t)(bm * 64 + row) * HIDN + kc * 8 + q * 2];
  float b = h0[(size_t)(bm * 64 + row) * HIDN + kc * 8 + q * 2 + 1];
  unsigned pay = (unsigned)f2bf(a) | ((unsigned)f2bf(b) << 16);
  thbuf[tid] = (unsigned long long)pay;                 // slot0: h0, tag 0
  thbuf[32768 + tid] = 0xFFFFFFFF00000000ull;           // slot1: poison
}

__launch_bounds__(256, 1)
__global__ void qlstm_main(
    const float* __restrict__ X, const float* __restrict__ c0,
    const float* __restrict__ Wf, const float* __restrict__ bf_,
    const float* __restrict__ thf, const float* __restrict__ scf,
    const float* __restrict__ Wi, const float* __restrict__ bi_,
    const float* __restrict__ thi, const float* __restrict__ sci,
    const float* __restrict__ Wu, const float* __restrict__ bu_,
    const float* __restrict__ thu, const float* __restrict__ scu,
    const float* __restrict__ Wo, const float* __restrict__ bo_,
    const float* __restrict__ tho, const float* __restrict__ sco,
    float* __restrict__ out,
    unsigned long long* __restrict__ thbuf) {
  const int tid = threadIdx.x;
  const int wave = tid >> 6;
  const int lane = tid & 63;
  const int quad = lane >> 4;
  const int col = lane & 15;          // MFMA n-index / C col / A m-index
  const int bm = blockIdx.x & 3;      // batch group (64 rows)
  const int js = blockIdx.x >> 2;     // hidden slice (16 cols)

  // ---- resident weight fragments (bf16), loaded once ----
  // B-frag for 16x16x32: B[k = quad*8 + j][n = col]; B[k][n] = W_g[js*16+n][k]
  s16x8 wx[4][8], wh[4][8];
  {
    const float* Wg[4] = {Wf, Wi, Wu, Wo};
#pragma unroll
    for (int g = 0; g < 4; ++g) {
      const float* wr = Wg[g] + (size_t)(js * 16 + col) * DTOT + quad * 8;
#pragma unroll
      for (int s = 0; s < 16; ++s) {
        float4 p0 = *(const float4*)(wr + s * 32);
        float4 p1 = *(const float4*)(wr + s * 32 + 4);
        s16x8 fr;
        fr[0] = (short)f2bf(p0.x); fr[1] = (short)f2bf(p0.y);
        fr[2] = (short)f2bf(p0.z); fr[3] = (short)f2bf(p0.w);
        fr[4] = (short)f2bf(p1.x); fr[5] = (short)f2bf(p1.y);
        fr[6] = (short)f2bf(p1.z); fr[7] = (short)f2bf(p1.w);
        if (s < 8) wx[g][s] = fr; else wh[g][s - 8] = fr;
      }
    }
  }
  float th[4], sc[4], bi[4];
  {
    const float* Tg[4] = {thf, thi, thu, tho};
    const float* Sg[4] = {scf, sci, scu, sco};
    const float* Bg[4] = {bf_, bi_, bu_, bo_};
#pragma unroll
    for (int g = 0; g < 4; ++g) {
      th[g] = Tg[g][js * 16 + col];
      sc[g] = Sg[g][js * 16 + col];
      bi[g] = Bg[g][js * 16 + col];
    }
  }

  // c state: C/D layout row = quad*4 + r, col = lane&15
  const int browq = bm * 64 + wave * 16 + quad * 4;
  float c[4];
#pragma unroll
  for (int r = 0; r < 4; ++r)
    c[r] = c0[(size_t)(browq + r) * HIDN + js * 16 + col];

  const float* Xrow = X + (size_t)(bm * 64 + wave * 16 + col) * IN_DIMX + quad * 8;
  const int kc_out = js * 2 + (col >> 3);
  const int jsub = col & 7;
  const int rowA = wave * 16 + col;   // A-frag batch row for this lane

#pragma clang loop unroll(disable)
  for (int t = 0; t < SEQ; ++t) {
    const unsigned long long* hsrc =
        thbuf + ((size_t)((t & 1) * 4 + bm)) * 8192;

    // ---- issue the tagged h(t) loads FIRST (they double as the poll) ----
    unsigned long long q64[32];
#pragma unroll
    for (int s = 0; s < 8; ++s) {
      const unsigned long long* p =
          hsrc + ((size_t)((s * 4 + quad) * 64 + rowA)) * 4;
#pragma unroll
      for (int j = 0; j < 4; ++j)
        q64[s * 4 + j] = __hip_atomic_load(p + j, __ATOMIC_RELAXED,
                                           __HIP_MEMORY_SCOPE_AGENT);
    }

    // ---- x side: load, convert, MFMA — overlaps the h flight time ----
    float4 xv[8][2];
    {
      const float* xb = Xrow + (size_t)t * BATCH * IN_DIMX;
#pragma unroll
      for (int s = 0; s < 8; ++s) {
        xv[s][0] = *(const float4*)(xb + s * 32);
        xv[s][1] = *(const float4*)(xb + s * 32 + 4);
      }
    }
    s16x8 xf[8];
#pragma unroll
    for (int s = 0; s < 8; ++s) {
      s16x8 fr;
      fr[0] = (short)f2bf(xv[s][0].x); fr[1] = (short)f2bf(xv[s][0].y);
      fr[2] = (short)f2bf(xv[s][0].z); fr[3] = (short)f2bf(xv[s][0].w);
      fr[4] = (short)f2bf(xv[s][1].x); fr[5] = (short)f2bf(xv[s][1].y);
      fr[6] = (short)f2bf(xv[s][1].z); fr[7] = (short)f2bf(xv[s][1].w);
      xf[s] = fr;
    }

    f32x4 acc[4];
#pragma unroll
    for (int g = 0; g < 4; ++g) acc[g] = (f32x4){bi[g], bi[g], bi[g], bi[g]};

#pragma unroll
    for (int s = 0; s < 8; ++s) {
#pragma unroll
      for (int g = 0; g < 4; ++g)
        acc[g] = __builtin_amdgcn_mfma_f32_16x16x32_bf16(xf[s], wx[g][s], acc[g], 0, 0, 0);
    }

    // ---- verify tags; reload-all until every word carries tag t ----
    {
      const unsigned long long want = (unsigned long long)(unsigned)t;
      for (;;) {
        unsigned bad = 0;
#pragma unroll
        for (int i = 0; i < 32; ++i)
          bad |= (unsigned)((q64[i] >> 32) != want);
        if (!bad) break;
#pragma unroll
        for (int s = 0; s < 8; ++s) {
          const unsigned long long* p =
              hsrc + ((size_t)((s * 4 + quad) * 64 + rowA)) * 4;
#pragma unroll
          for (int j = 0; j < 4; ++j)
            q64[s * 4 + j] = __hip_atomic_load(p + j, __ATOMIC_RELAXED,
                                               __HIP_MEMORY_SCOPE_AGENT);
        }
      }
    }

    // ---- h-side MFMAs from verified payloads ----
#pragma unroll
    for (int s = 0; s < 8; ++s) {
      union { unsigned w[4]; s16x8 v; } fu;
#pragma unroll
      for (int j = 0; j < 4; ++j) fu.w[j] = (unsigned)q64[s * 4 + j];
#pragma unroll
      for (int g = 0; g < 4; ++g)
        acc[g] = __builtin_amdgcn_mfma_f32_16x16x32_bf16(fu.v, wh[g][s], acc[g], 0, 0, 0);
    }

    // ---- gates + state update; acc tiles 0..3 = f,i,u,o ----
    float hh[4];
#pragma unroll
    for (int r = 0; r < 4; ++r) {
      float fg = sigm(sigm(__sinf(acc[0][r] * th[0]) * sc[0]));
      float ig = sigm(sigm(__sinf(acc[1][r] * th[1]) * sc[1]));
      float gg = tanh_fast(sigm(__sinf(acc[2][r] * th[2]) * sc[2]));
      float og = sigm(sigm(__sinf(acc[3][r] * th[3]) * sc[3]));
      float cn = fg * c[r] + ig * gg;
      c[r] = cn;
      hh[r] = og * tanh_fast(cn);
    }

    // ---- publish h(t+1) FIRST (critical path): tagged u64 atomic stores,
    // fire-and-forget. Even lanes carry the (even,odd) bf16 pair. ----
    {
      unsigned long long* hdst =
          thbuf + ((size_t)(((t + 1) & 1) * 4 + bm)) * 8192;
      const unsigned long long tagv =
          ((unsigned long long)(unsigned)(t + 1)) << 32;
#pragma unroll
      for (int r = 0; r < 4; ++r) {
        float ph = __shfl_xor(hh[r], 1);
        if ((col & 1) == 0) {
          unsigned pay = (unsigned)f2bf(hh[r]) | ((unsigned)f2bf(ph) << 16);
          __hip_atomic_store(
              hdst + ((size_t)(kc_out * 64 + wave * 16 + quad * 4 + r)) * 4 +
                  (jsub >> 1),
              (unsigned long long)pay | tagv,
              __ATOMIC_RELAXED, __HIP_MEMORY_SCOPE_AGENT);
        }
      }
    }

    // ---- out stores (off the critical path) ----
    {
      float* orow = out + (size_t)t * BATCH * HIDN;
#pragma unroll
      for (int r = 0; r < 4; ++r) {
        int brow = browq + r;
        orow[(size_t)brow * HIDN + js * 16 + col] = hh[r];
        if (t == SEQ - 1) {
          out[(size_t)SEQ * BATCH * HIDN + (size_t)brow * HIDN + js * 16 + col] = hh[r];
          out[(size_t)SEQ * BATCH * HIDN + (size_t)BATCH * HIDN +
              (size_t)brow * HIDN + js * 16 + col] = c[r];
        }
      }
    }
  }
}

extern "C" void kernel_launch(void* const* d_in, const int* in_sizes, int n_in,
                              void* d_out, int out_size, void* d_ws, size_t ws_size,
                              hipStream_t stream) {
  (void)in_sizes; (void)n_in; (void)out_size; (void)ws_size;
  const float* X   = (const float*)d_in[0];
  const float* h0  = (const float*)d_in[1];
  const float* c0  = (const float*)d_in[2];
  const float* Wf  = (const float*)d_in[3];
  const float* bf_ = (const float*)d_in[4];
  const float* thf = (const float*)d_in[5];
  const float* scf = (const float*)d_in[6];
  const float* Wi  = (const float*)d_in[7];
  const float* bi_ = (const float*)d_in[8];
  const float* thi = (const float*)d_in[9];
  const float* sci = (const float*)d_in[10];
  const float* Wu  = (const float*)d_in[11];
  const float* bu_ = (const float*)d_in[12];
  const float* thu = (const float*)d_in[13];
  const float* scu = (const float*)d_in[14];
  const float* Wo  = (const float*)d_in[15];
  const float* bo_ = (const float*)d_in[16];
  const float* tho = (const float*)d_in[17];
  const float* sco = (const float*)d_in[18];
  float* out = (float*)d_out;

  unsigned long long* thbuf = (unsigned long long*)d_ws;  // 2*4*8192 u64 = 512 KB

  hipLaunchKernelGGL(qlstm_prep, dim3(256), dim3(256), 0, stream, h0, thbuf);

  // Plain launch: 64 blocks, 1 block/CU -> all resident on a 256-CU device.
  hipLaunchKernelGGL(qlstm_main, dim3(64), dim3(256), 0, stream,
                     X, c0, Wf, bf_, thf, scf, Wi, bi_, thi, sci,
                     Wu, bu_, thu, scu, Wo, bo_, tho, sco,
                     out, thbuf);
}

// Round 3
// 3027.306 us; speedup vs baseline: 1.3588x; 1.3588x over previous
//
#include <hip/hip_runtime.h>
#include <cstdint>
#include <cstddef>

// QLSTM on MI355X. Persistent kernel, 64 WGs (4 batch-groups x 16 hidden-
// slices), 1 block/CU. Weights resident in VGPRs (bf16 B-fragments).
//
// R3: PER-WAVE decoupled handshake. Consumer wave w only needs batch rows
// [16w,16w+16), produced exclusively by wave w of the 16 js-peer blocks.
// So the computation is 16 independent chains (4 bm x 4 wave-rows); the
// block barriers in R0/R1 coupled groups of 4 chains for no reason.
//   producer wave: payload u32 atomic stores (agent, write-through) ->
//                  s_waitcnt vmcnt(0) (wave-local) -> lane0 flag store.
//   consumer wave: x loads -> 16-lane divergent spin on 16 same-wave flags
//                  -> issue 32 h u32 loads -> convert x + x-MFMAs in the
//                  h flight window -> h-MFMAs -> gates -> publish.
// Zero __syncthreads in the step loop. No acquire/release cache-wide ops.
//
// Overwrite safety (2-slot ping-pong, per-wave): wave (bm,w,js) writes slot
// (t+1)&1 at step t only after its step-t h loads completed (they feed the
// MFMAs whose results feed the publish data). A writer reaches step t+2's
// publish (overwriting h(t)'s slot with h(t+3)... indices: it writes h(t+2+1)
// only after consuming h(t+2), which required all peers to publish h(t+2),
// which they did only after their h(t+1)-loads... inductively no slot is
// overwritten while readable. Same invariant as R0/R1, at wave granularity.
//
// Replay safety: flags are t-indexed and zeroed by the prep kernel each
// launch; slot0 of hbuf is rewritten with h0 by prep; t=0 skips the poll.

#define SEQ 512
#define BATCH 256
#define IN_DIMX 256
#define HIDN 256
#define DTOT 512

typedef float f32x4 __attribute__((ext_vector_type(4)));
typedef short s16x8 __attribute__((ext_vector_type(8)));

__device__ __forceinline__ unsigned short f2bf(float f) {
  unsigned u = __builtin_bit_cast(unsigned, f);
  u += 0x7FFFu + ((u >> 16) & 1u);   // RNE to bf16
  return (unsigned short)(u >> 16);
}

__device__ __forceinline__ float sigm(float x) {
  return __builtin_amdgcn_rcpf(1.0f + __expf(-x));
}
__device__ __forceinline__ float tanh_fast(float x) {
  return 1.0f - 2.0f * __builtin_amdgcn_rcpf(1.0f + __expf(2.0f * x));
}

// hbuf: u32 [2 slot][4 bm][32 kc][64 row][4 q]; u32 = bf16 pair
//   (h[row, kc*8+2q], h[row, kc*8+2q+1]). Slot s holds h(t), (t&1)==s.
// flags: int [SEQ+1][4 bm][4 wave][16 js].
__global__ void qlstm_prep(const float* __restrict__ h0,
                           unsigned* __restrict__ hbuf,
                           int* __restrict__ flags) {
  int tid = blockIdx.x * blockDim.x + threadIdx.x;   // 65536 threads
  // zero flags: (SEQ+1)*256 = 131328 ints
  flags[tid] = 0;
  flags[tid + 65536] = 0;
  if (tid < 131328 - 131072) flags[tid + 131072] = 0;
  if (tid < 32768) {
    int bm = tid >> 13, rem = tid & 8191;
    int kc = rem >> 8, row = (rem >> 2) & 63, q = rem & 3;
    float a = h0[(size_t)(bm * 64 + row) * HIDN + kc * 8 + q * 2];
    float b = h0[(size_t)(bm * 64 + row) * HIDN + kc * 8 + q * 2 + 1];
    hbuf[tid] = (unsigned)f2bf(a) | ((unsigned)f2bf(b) << 16);
  }
}

__launch_bounds__(256, 1)
__global__ void qlstm_main(
    const float* __restrict__ X, const float* __restrict__ c0,
    const float* __restrict__ Wf, const float* __restrict__ bf_,
    const float* __restrict__ thf, const float* __restrict__ scf,
    const float* __restrict__ Wi, const float* __restrict__ bi_,
    const float* __restrict__ thi, const float* __restrict__ sci,
    const float* __restrict__ Wu, const float* __restrict__ bu_,
    const float* __restrict__ thu, const float* __restrict__ scu,
    const float* __restrict__ Wo, const float* __restrict__ bo_,
    const float* __restrict__ tho, const float* __restrict__ sco,
    float* __restrict__ out,
    unsigned* __restrict__ hbuf,
    int* __restrict__ flags) {
  const int tid = threadIdx.x;
  const int wave = tid >> 6;
  const int lane = tid & 63;
  const int quad = lane >> 4;
  const int col = lane & 15;          // MFMA n-index / C col / A m-index
  const int bm = blockIdx.x & 3;      // batch group (64 rows)
  const int js = blockIdx.x >> 2;     // hidden slice (16 cols)

  // ---- resident weight fragments (bf16), loaded once ----
  // B-frag for 16x16x32: B[k = quad*8 + j][n = col]; B[k][n] = W_g[js*16+n][k]
  s16x8 wx[4][8], wh[4][8];
  {
    const float* Wg[4] = {Wf, Wi, Wu, Wo};
#pragma unroll
    for (int g = 0; g < 4; ++g) {
      const float* wr = Wg[g] + (size_t)(js * 16 + col) * DTOT + quad * 8;
#pragma unroll
      for (int s = 0; s < 16; ++s) {
        float4 p0 = *(const float4*)(wr + s * 32);
        float4 p1 = *(const float4*)(wr + s * 32 + 4);
        s16x8 fr;
        fr[0] = (short)f2bf(p0.x); fr[1] = (short)f2bf(p0.y);
        fr[2] = (short)f2bf(p0.z); fr[3] = (short)f2bf(p0.w);
        fr[4] = (short)f2bf(p1.x); fr[5] = (short)f2bf(p1.y);
        fr[6] = (short)f2bf(p1.z); fr[7] = (short)f2bf(p1.w);
        if (s < 8) wx[g][s] = fr; else wh[g][s - 8] = fr;
      }
    }
  }
  float th[4], sc[4], bi[4];
  {
    const float* Tg[4] = {thf, thi, thu, tho};
    const float* Sg[4] = {scf, sci, scu, sco};
    const float* Bg[4] = {bf_, bi_, bu_, bo_};
#pragma unroll
    for (int g = 0; g < 4; ++g) {
      th[g] = Tg[g][js * 16 + col];
      sc[g] = Sg[g][js * 16 + col];
      bi[g] = Bg[g][js * 16 + col];
    }
  }

  // c state: C/D layout row = quad*4 + r, col = lane&15
  const int browq = bm * 64 + wave * 16 + quad * 4;
  float c[4];
#pragma unroll
  for (int r = 0; r < 4; ++r)
    c[r] = c0[(size_t)(browq + r) * HIDN + js * 16 + col];

  const float* Xrow = X + (size_t)(bm * 64 + wave * 16 + col) * IN_DIMX + quad * 8;
  const int kc_out = js * 2 + (col >> 3);
  const int jsub = col & 7;
  const int rowA = wave * 16 + col;   // A-frag batch row for this lane

#pragma clang loop unroll(disable)
  for (int t = 0; t < SEQ; ++t) {
    // ---- 1. issue x loads (arrive during the poll) ----
    float4 xv[8][2];
    {
      const float* xb = Xrow + (size_t)t * BATCH * IN_DIMX;
#pragma unroll
      for (int s = 0; s < 8; ++s) {
        xv[s][0] = *(const float4*)(xb + s * 32);
        xv[s][1] = *(const float4*)(xb + s * 32 + 4);
      }
    }

    // ---- 2. per-wave poll: 16 lanes spin on the 16 same-wave producer
    // flags. Divergent loop; exec-mask reconverges when all lanes exit.
    // No __syncthreads. ----
    if (t > 0) {
      if (lane < 16) {
        const int* fp = flags + (((size_t)t * 4 + bm) * 4 + wave) * 16 + lane;
        while (__hip_atomic_load(fp, __ATOMIC_RELAXED,
                                 __HIP_MEMORY_SCOPE_AGENT) == 0) {
          __builtin_amdgcn_s_sleep(1);
        }
      }
    }

    // ---- 3. issue all 32 h payload loads (the chain's data RT) ----
    const unsigned* hsrc = hbuf + ((size_t)((t & 1) * 4 + bm)) * 8192;
    unsigned hq[32];
#pragma unroll
    for (int s = 0; s < 8; ++s) {
      const unsigned* p = hsrc + ((size_t)((s * 4 + quad) * 64 + rowA)) * 4;
#pragma unroll
      for (int j = 0; j < 4; ++j)
        hq[s * 4 + j] = __hip_atomic_load(p + j, __ATOMIC_RELAXED,
                                          __HIP_MEMORY_SCOPE_AGENT);
    }

    // ---- 4. convert x + x-MFMAs inside the h flight window ----
    f32x4 acc[4];
#pragma unroll
    for (int g = 0; g < 4; ++g) acc[g] = (f32x4){bi[g], bi[g], bi[g], bi[g]};

#pragma unroll
    for (int s = 0; s < 8; ++s) {
      s16x8 fr;
      fr[0] = (short)f2bf(xv[s][0].x); fr[1] = (short)f2bf(xv[s][0].y);
      fr[2] = (short)f2bf(xv[s][0].z); fr[3] = (short)f2bf(xv[s][0].w);
      fr[4] = (short)f2bf(xv[s][1].x); fr[5] = (short)f2bf(xv[s][1].y);
      fr[6] = (short)f2bf(xv[s][1].z); fr[7] = (short)f2bf(xv[s][1].w);
#pragma unroll
      for (int g = 0; g < 4; ++g)
        acc[g] = __builtin_amdgcn_mfma_f32_16x16x32_bf16(fr, wx[g][s], acc[g], 0, 0, 0);
    }

    // ---- 5. h-MFMAs ----
#pragma unroll
    for (int s = 0; s < 8; ++s) {
      union { unsigned w[4]; s16x8 v; } fu;
#pragma unroll
      for (int j = 0; j < 4; ++j) fu.w[j] = hq[s * 4 + j];
#pragma unroll
      for (int g = 0; g < 4; ++g)
        acc[g] = __builtin_amdgcn_mfma_f32_16x16x32_bf16(fu.v, wh[g][s], acc[g], 0, 0, 0);
    }

    // ---- 6. gates + state update; acc tiles 0..3 = f,i,u,o ----
    float hh[4];
#pragma unroll
    for (int r = 0; r < 4; ++r) {
      float fg = sigm(sigm(__sinf(acc[0][r] * th[0]) * sc[0]));
      float ig = sigm(sigm(__sinf(acc[1][r] * th[1]) * sc[1]));
      float gg = tanh_fast(sigm(__sinf(acc[2][r] * th[2]) * sc[2]));
      float og = sigm(sigm(__sinf(acc[3][r] * th[3]) * sc[3]));
      float cn = fg * c[r] + ig * gg;
      c[r] = cn;
      hh[r] = og * tanh_fast(cn);
    }

    // ---- 7. publish h(t+1): payload u32 stores -> wave-local vmcnt drain
    // -> lane0 flag store. Fire-and-forget, no barrier. ----
    {
      unsigned* hdst = hbuf + ((size_t)(((t + 1) & 1) * 4 + bm)) * 8192;
#pragma unroll
      for (int r = 0; r < 4; ++r) {
        float ph = __shfl_xor(hh[r], 1);
        if ((col & 1) == 0) {
          unsigned pay = (unsigned)f2bf(hh[r]) | ((unsigned)f2bf(ph) << 16);
          __hip_atomic_store(
              hdst + ((size_t)(kc_out * 64 + wave * 16 + quad * 4 + r)) * 4 +
                  (jsub >> 1),
              pay, __ATOMIC_RELAXED, __HIP_MEMORY_SCOPE_AGENT);
        }
      }
      asm volatile("s_waitcnt vmcnt(0)" ::: "memory");
      if (lane == 0) {
        __hip_atomic_store(
            flags + (((size_t)(t + 1) * 4 + bm) * 4 + wave) * 16 + js, 1,
            __ATOMIC_RELAXED, __HIP_MEMORY_SCOPE_AGENT);
      }
    }

    // ---- 8. out stores (off the chain) ----
    {
      float* orow = out + (size_t)t * BATCH * HIDN;
#pragma unroll
      for (int r = 0; r < 4; ++r) {
        int brow = browq + r;
        orow[(size_t)brow * HIDN + js * 16 + col] = hh[r];
        if (t == SEQ - 1) {
          out[(size_t)SEQ * BATCH * HIDN + (size_t)brow * HIDN + js * 16 + col] = hh[r];
          out[(size_t)SEQ * BATCH * HIDN + (size_t)BATCH * HIDN +
              (size_t)brow * HIDN + js * 16 + col] = c[r];
        }
      }
    }
  }
}

extern "C" void kernel_launch(void* const* d_in, const int* in_sizes, int n_in,
                              void* d_out, int out_size, void* d_ws, size_t ws_size,
                              hipStream_t stream) {
  (void)in_sizes; (void)n_in; (void)out_size; (void)ws_size;
  const float* X   = (const float*)d_in[0];
  const float* h0  = (const float*)d_in[1];
  const float* c0  = (const float*)d_in[2];
  const float* Wf  = (const float*)d_in[3];
  const float* bf_ = (const float*)d_in[4];
  const float* thf = (const float*)d_in[5];
  const float* scf = (const float*)d_in[6];
  const float* Wi  = (const float*)d_in[7];
  const float* bi_ = (const float*)d_in[8];
  const float* thi = (const float*)d_in[9];
  const float* sci = (const float*)d_in[10];
  const float* Wu  = (const float*)d_in[11];
  const float* bu_ = (const float*)d_in[12];
  const float* thu = (const float*)d_in[13];
  const float* scu = (const float*)d_in[14];
  const float* Wo  = (const float*)d_in[15];
  const float* bo_ = (const float*)d_in[16];
  const float* tho = (const float*)d_in[17];
  const float* sco = (const float*)d_in[18];
  float* out = (float*)d_out;

  unsigned* hbuf = (unsigned*)d_ws;                        // 2*4*8192 u32 = 256 KB
  int* flags = (int*)((char*)d_ws + 262144);               // (SEQ+1)*256 ints = 513 KB

  hipLaunchKernelGGL(qlstm_prep, dim3(256), dim3(256), 0, stream, h0, hbuf, flags);

  // Plain launch: 64 blocks, 1 block/CU -> all resident on a 256-CU device.
  hipLaunchKernelGGL(qlstm_main, dim3(64), dim3(256), 0, stream,
                     X, c0, Wf, bf_, thf, scf, Wi, bi_, thi, sci,
                     Wu, bu_, thu, scu, Wo, bo_, tho, sco,
                     out, hbuf, flags);
}